// Round 3
// baseline (4691.190 us; speedup 1.0000x reference)
//
#include <hip/hip_runtime.h>

// ---------------------------------------------------------------------------
// Bidirectional GRU (Keras v2, reset_after=True) + dense tanh head, MI355X.
// B=128, T=512, D=300, U=300, DENSE=100.
//
//   k_prep : repack W/U -> bf16 fragments-source layout, 12 col-chunks/dir
//            (chunk = [z 25 | r 25 | h 25 | pad 5] = 80 cols), K pad 300->320.
//            Also WdT [112][640] bf16, biases (permuted) f32.
//   k_xbf  : x -> bf16 [65536][320] (K-padded) + mask[b,t] = any(x!=0)
//   k_scan : recurrence. Grid = 2 dir x 4 batch(32 rows) x 12 col-chunks = 96.
//            U-chunk AND W-chunk fragments resident in LDS (51 KB each).
//            Waves 0-1: h@U GEMM. Waves 2-3: x@W GEMM (x A-frags loaded
//            straight from global, prefetched before the peer-flag wait).
//            Cross-block h via agent-scope release/acquire flags; h carry fp32.
//   k_dense: out = tanh(h_all @ Wd + bd), static 22.5 KB LDS.
//
// Diagnostics: if ws too small or LDS-attr fails, out[] = code (ws_MB +100000
// if attr failed) so the harness absmax reveals the cause.
// ---------------------------------------------------------------------------

typedef float f32x4 __attribute__((ext_vector_type(4)));
typedef short short8 __attribute__((ext_vector_type(8)));
typedef unsigned short u16;
typedef unsigned int u32;
typedef unsigned long long u64;

#define MFMA16(a, b, c) __builtin_amdgcn_mfma_f32_16x16x32_bf16((a), (b), (c), 0, 0, 0)

__device__ __forceinline__ u16 f2bf(float f) {
  u32 u = __float_as_uint(f);
  u = u + 0x7FFFu + ((u >> 16) & 1u);   // RNE
  return (u16)(u >> 16);
}
__device__ __forceinline__ float bf2f(u16 h) {
  return __uint_as_float(((u32)h) << 16);
}
__device__ __forceinline__ float sigm(float x) { return 1.f / (1.f + __expf(-x)); }
__device__ __forceinline__ float tanhx(float x) { return 1.f - 2.f / (__expf(2.f * x) + 1.f); }

// ---------------- workspace layout (bytes) ----------------
#define OFF_WT       0ULL          // bf16 [2][12][80][320]   1228800
#define OFF_UT       1228800ULL    // bf16 [2][12][80][320]   1228800
#define OFF_B0P      2457600ULL    // f32  [2][960]           7680
#define OFF_B1P      2465280ULL    // f32  [2][960]           7680
#define OFF_WDT      2472960ULL    // bf16 [112][640]         143360
#define OFF_BDP      2616320ULL    // f32  [112] pad          512
#define OFF_MASK     2616832ULL    // f32  [65536]            262144
#define OFF_HSTATE   2878976ULL    // bf16 [2][4][2][32][320] 327680
#define OFF_FLAGS    3206656ULL    // u32  [2][4][512]        16384
#define OFF_XBF      3223040ULL    // bf16 [65536][320]       41943040
#define OFF_HALL     45166080ULL   // bf16 [65536][600]       78643200
#define WS_NEED      123809280ULL  // ~118 MB

// ---------------------------------------------------------------------------
__global__ __launch_bounds__(256) void k_sentinel(float* __restrict__ out,
                                                  float code, int n) {
  int i = blockIdx.x * 256 + threadIdx.x;
  if (i < n) out[i] = code;
}

// ---------------------------------------------------------------------------
// k_prep: weight repack. chunk cc (0..11): col lc<75 -> gate g=lc/25,
// j = cc*25 + lc%25; K pad 300->320.
// ---------------------------------------------------------------------------
__global__ __launch_bounds__(256) void k_prep(
    const float* __restrict__ Wf, const float* __restrict__ Uf,
    const float* __restrict__ bfp, const float* __restrict__ Wb,
    const float* __restrict__ Ub, const float* __restrict__ bbp,
    const float* __restrict__ Wd, const float* __restrict__ bd,
    u16* __restrict__ WT, u16* __restrict__ UT,
    float* __restrict__ b0p, float* __restrict__ b1p,
    u16* __restrict__ WdT, float* __restrict__ bdp)
{
  const long long NWU = 2LL * 960 * 320;  // 614400
  const long long TOTAL = NWU * 2 + 1920 + 71680 + 112;
  for (long long i = (long long)blockIdx.x * 256 + threadIdx.x; i < TOTAL;
       i += 2048LL * 256) {
    long long r = i;
    if (r < NWU) {  // WT
      int d = (int)(r / 307200); int q = (int)(r % 307200);
      int c = q / 320, k = q % 320;
      int cc = c / 80, lc = c % 80;
      float v = 0.f;
      if (k < 300 && lc < 75) {
        int g = lc / 25, jp = lc % 25;
        const float* W = d ? Wb : Wf;
        v = W[k * 900 + g * 300 + cc * 25 + jp];
      }
      WT[r] = f2bf(v);
      continue;
    }
    r -= NWU;
    if (r < NWU) {  // UT
      int d = (int)(r / 307200); int q = (int)(r % 307200);
      int c = q / 320, k = q % 320;
      int cc = c / 80, lc = c % 80;
      float v = 0.f;
      if (k < 300 && lc < 75) {
        int g = lc / 25, jp = lc % 25;
        const float* U = d ? Ub : Uf;
        v = U[k * 900 + g * 300 + cc * 25 + jp];
      }
      UT[r] = f2bf(v);
      continue;
    }
    r -= NWU;
    if (r < 1920) {  // biases (permuted): b0 row 0, b1 row 1
      int d = (int)(r / 960); int c = (int)(r % 960);
      int cc = c / 80, lc = c % 80;
      float v0 = 0.f, v1 = 0.f;
      if (lc < 75) {
        int g = lc / 25, jp = lc % 25;
        const float* B = d ? bbp : bfp;
        int sc = g * 300 + cc * 25 + jp;
        v0 = B[sc]; v1 = B[900 + sc];
      }
      b0p[r] = v0; b1p[r] = v1;
      continue;
    }
    r -= 1920;
    if (r < 71680) {  // WdT [112][640] (transposed, padded)
      int n = (int)(r / 640); int k = (int)(r % 640);
      float v = (n < 100 && k < 600) ? Wd[k * 100 + n] : 0.f;
      WdT[r] = f2bf(v);
      continue;
    }
    r -= 71680;
    if (r < 112) bdp[r] = (r < 100) ? bd[r] : 0.f;
  }
}

// ---------------------------------------------------------------------------
// k_xbf: x -> bf16 (K-padded 320) + mask. One wave per (b,t) row.
// ---------------------------------------------------------------------------
__global__ __launch_bounds__(256) void k_xbf(const float* __restrict__ x,
                                             u16* __restrict__ xbf,
                                             float* __restrict__ mask)
{
  int row = blockIdx.x * 4 + (threadIdx.x >> 6);
  int l = threadIdx.x & 63;
  const float* xr = x + (size_t)row * 300;
  u16* xo = xbf + (size_t)row * 320;
  int p = 0;
#pragma unroll
  for (int c = 0; c < 5; ++c) {
    int k = l + c * 64;
    float v = (k < 300) ? xr[k] : 0.f;
    p |= (v != 0.f);
    xo[k] = f2bf(v);
  }
  unsigned long long b = __ballot(p);
  if (l == 0) mask[row] = (b != 0ULL) ? 1.f : 0.f;
}

// ---------------------------------------------------------------------------
// k_scan: grid 96: d = bid/48, bc = (bid%48)/12, cc = bid%12.
// 256 thr = 4 waves: w 0,1 = rec GEMM rows 0-15/16-31; w 2,3 = x GEMM.
// LDS: Ufrag 51200 | Wfrag 51200 | hS 20480 (swz) | recS 10240 | xgS 10240
//      = 143360 B.
// ---------------------------------------------------------------------------
__global__ __launch_bounds__(256, 1) void k_scan(
    const u16* __restrict__ UTg, const u16* __restrict__ WTg,
    const float* __restrict__ b0p, const float* __restrict__ b1p,
    const u16* __restrict__ xbf, const float* __restrict__ mask,
    u16* __restrict__ h_state, u16* __restrict__ h_all, u32* __restrict__ flags)
{
  extern __shared__ char smem[];
  u16*   Ufrag = (u16*)smem;               // 51200 B
  u16*   Wfrag = (u16*)(smem + 51200);     // 51200 B
  char*  hS    = smem + 102400;            // 20480 B
  float* recS  = (float*)(smem + 122880);  // 10240 B  [32][80] f32
  float* xgS   = (float*)(smem + 133120);  // 10240 B  [32][80] f32

  const int tid = threadIdx.x;
  const int l = tid & 63;
  const int w = tid >> 6;
  const bool is_x = (w >= 2);
  const int wm = w & 1;
  const int lc15 = l & 15, lq = l >> 4;

  const int bid = blockIdx.x;
  const int d = bid / 48;
  const int bc = (bid % 48) / 12;
  const int cc = bid % 12;

  // ---- stage U and W fragments (once): 3200 uint4 each ----
  {
    const u16* Ub = UTg + (size_t)(d * 12 + cc) * 80 * 320;
    const u16* Wb = WTg + (size_t)(d * 12 + cc) * 80 * 320;
    for (int u = tid; u < 3200; u += 256) {
      int fi = u >> 6, ll = u & 63;
      int nt = fi / 10, kt = fi % 10;
      int col = nt * 16 + (ll & 15);
      int k = kt * 32 + ((ll >> 4) << 3);
      *(uint4*)(Ufrag + (size_t)u * 8) = *(const uint4*)(Ub + (size_t)col * 320 + k);
      *(uint4*)(Wfrag + (size_t)u * 8) = *(const uint4*)(Wb + (size_t)col * 320 + k);
    }
  }

  // per-wave bias values: rec waves -> b1, x waves -> b0
  float bv[5];
#pragma unroll
  for (int nt = 0; nt < 5; ++nt) {
    int col = d * 960 + cc * 80 + nt * 16 + lc15;
    bv[nt] = is_x ? b0p[col] : b1p[col];
  }

  // gate item mapping: 800 items = 32 rows x 25 j
  int g_row[4], g_jp[4]; bool g_act[4];
#pragma unroll
  for (int it = 0; it < 4; ++it) {
    int i2 = tid + it * 256;
    g_act[it] = (i2 < 800);
    int rr = i2 / 25; if (rr > 31) rr = 31;
    g_row[it] = rr; g_jp[it] = i2 - (i2 / 25) * 25;
  }
  float hold[4];
#pragma unroll
  for (int it = 0; it < 4; ++it) hold[it] = 0.f;

  u16* hsA = h_state + (size_t)(d * 4 + bc) * 2 * 32 * 320;
  u32* flg = flags + (d * 4 + bc) * 512;

  __syncthreads();

  for (int t = 0; t < 512; ++t) {
    const int t_eff = d ? (511 - t) : t;

    // ---- prefetch (peer-independent): x A-frags direct from global ----
    short8 xF[10];
    if (is_x) {
      int row_b = bc * 32 + wm * 16 + lc15;
      const u16* xr = xbf + ((size_t)row_b * 512 + t_eff) * 320 + (lq << 3);
#pragma unroll
      for (int kt = 0; kt < 10; ++kt) xF[kt] = *(const short8*)(xr + kt * 32);
    }
    float mk[4];
#pragma unroll
    for (int it = 0; it < 4; ++it)
      mk[it] = g_act[it] ? mask[(size_t)(bc * 32 + g_row[it]) * 512 + t_eff] : 1.f;

    // ---- x GEMM (runs during peer wait) ----
    if (is_x) {
      f32x4 acc[5];
#pragma unroll
      for (int i = 0; i < 5; ++i) { f32x4 z = {0.f, 0.f, 0.f, 0.f}; acc[i] = z; }
#pragma unroll
      for (int kt = 0; kt < 10; ++kt) {
#pragma unroll
        for (int nt = 0; nt < 5; ++nt) {
          short8 bF = *(const short8*)(Wfrag + ((size_t)((nt * 10 + kt) * 64 + l)) * 8);
          acc[nt] = MFMA16(xF[kt], bF, acc[nt]);
        }
      }
#pragma unroll
      for (int nt = 0; nt < 5; ++nt) {
#pragma unroll
        for (int e = 0; e < 4; ++e)
          xgS[(wm * 16 + lq * 4 + e) * 80 + nt * 16 + lc15] = acc[nt][e] + bv[nt];
      }
    }

    // ---- wait for peers' step t-1 completion ----
    if (t > 0 && tid == 0) {
      while (__hip_atomic_load(flg + (t - 1), __ATOMIC_ACQUIRE,
                               __HIP_MEMORY_SCOPE_AGENT) < 12u)
        __builtin_amdgcn_s_sleep(2);
    }
    __syncthreads();

    // ---- stage h (parity t&1) into swizzled LDS ----
    {
      const u16* hsrc = hsA + ((size_t)(t & 1)) * 32 * 320;
#pragma unroll
      for (int u0 = 0; u0 < 10; ++u0) {
        int u = tid + u0 * 256;
        int row = u / 80, c4 = u - (u / 80) * 80;
        u64 v = __hip_atomic_load((const u64*)(hsrc + (size_t)row * 320 + c4 * 4),
                                  __ATOMIC_RELAXED, __HIP_MEMORY_SCOPE_AGENT);
        *(u64*)(hS + row * 640 + ((c4 * 8) ^ ((row & 7) << 4))) = v;
      }
    }
    __syncthreads();

    // ---- rec GEMM: h @ U ----
    if (!is_x) {
      const int r = wm * 16 + lc15;
      const int sw = (r & 7) << 4;
      const int rb = r * 640;
      f32x4 acc[5];
#pragma unroll
      for (int i = 0; i < 5; ++i) { f32x4 z = {0.f, 0.f, 0.f, 0.f}; acc[i] = z; }
#pragma unroll
      for (int kt = 0; kt < 10; ++kt) {
        short8 aF = *(const short8*)(hS + rb + ((kt * 64 + (lq << 4)) ^ sw));
#pragma unroll
        for (int nt = 0; nt < 5; ++nt) {
          short8 bF = *(const short8*)(Ufrag + ((size_t)((nt * 10 + kt) * 64 + l)) * 8);
          acc[nt] = MFMA16(aF, bF, acc[nt]);
        }
      }
#pragma unroll
      for (int nt = 0; nt < 5; ++nt) {
#pragma unroll
        for (int e = 0; e < 4; ++e)
          recS[(wm * 16 + lq * 4 + e) * 80 + nt * 16 + lc15] = acc[nt][e] + bv[nt];
      }
    }
    __syncthreads();

    // ---- gates (fp32), carry, stores ----
#pragma unroll
    for (int it = 0; it < 4; ++it) {
      if (g_act[it]) {
        int row = g_row[it], jp = g_jp[it];
        float xz = xgS[row * 80 + jp],      rz = recS[row * 80 + jp];
        float xr_ = xgS[row * 80 + 25 + jp], rr = recS[row * 80 + 25 + jp];
        float xh = xgS[row * 80 + 50 + jp],  rh = recS[row * 80 + 50 + jp];
        float z = sigm(xz + rz);
        float r = sigm(xr_ + rr);
        float hh = tanhx(xh + r * rh);
        float hn = z * hold[it] + (1.f - z) * hh;
        hn = (mk[it] != 0.f) ? hn : hold[it];
        hold[it] = hn;
        u16 hb = f2bf(hn);
        int jg = cc * 25 + jp;
        hsA[((size_t)((t + 1) & 1)) * 32 * 320 + (size_t)row * 320 + jg] = hb;
        size_t ridx = (size_t)(bc * 32 + row) * 512 + t_eff;
        h_all[ridx * 600 + d * 300 + jg] = hb;
      }
    }
    __syncthreads();  // forces vmcnt(0): all stores complete before flag
    if (tid == 0)
      __hip_atomic_fetch_add(flg + t, 1u, __ATOMIC_RELEASE, __HIP_MEMORY_SCOPE_AGENT);
  }
}

// ---------------------------------------------------------------------------
// k_dense: out = tanh(h_all @ Wd + bd). M=64 tile, static LDS 22.5 KB.
// ---------------------------------------------------------------------------
__global__ __launch_bounds__(256) void k_dense(
    const u16* __restrict__ h_all, const u16* __restrict__ WdT,
    const float* __restrict__ bdp, float* __restrict__ out)
{
  __shared__ u16 Bf[7 * 2 * 64 * 8];  // 14336 B
  __shared__ char A[8192];
  const int tid = threadIdx.x;
  const int l = tid & 63;
  const int w = tid >> 6;
  const int lc15 = l & 15, lq = l >> 4;
  const int mblk = blockIdx.x;

  f32x4 acc[7];
#pragma unroll
  for (int i = 0; i < 7; ++i) { f32x4 z = {0.f, 0.f, 0.f, 0.f}; acc[i] = z; }

  for (int kc = 0; kc < 10; ++kc) {
    // stage A [64 rows][64 k] swizzled
    for (int u = tid; u < 512; u += 256) {
      int row = u >> 3, oct = u & 7;
      int k0 = kc * 64 + oct * 8;
      uint4 v = {0u, 0u, 0u, 0u};
      if (k0 <= 592)
        v = *(const uint4*)(h_all + (size_t)(mblk * 64 + row) * 600 + k0);
      *(uint4*)(A + row * 128 + ((oct * 16) ^ ((row & 7) << 4))) = v;
    }
    // stage B frags for kt pair (kc*2, kc*2+1): 896 uint4
    for (int u = tid; u < 896; u += 256) {
      int idx = u >> 6, ll = u & 63;
      int nt = idx >> 1, ktp = idx & 1;
      int kt = kc * 2 + ktp;
      uint4 v = {0u, 0u, 0u, 0u};
      if (kt < 19) {
        int col = nt * 16 + (ll & 15);
        int k = kt * 32 + ((ll >> 4) << 3);
        v = *(const uint4*)(WdT + (size_t)col * 640 + k);
      }
      *(uint4*)(Bf + (size_t)u * 8) = v;
    }
    __syncthreads();
    const int r = w * 16 + lc15;
    const int swA = (r & 7) << 4;
#pragma unroll
    for (int ktp = 0; ktp < 2; ++ktp) {
      if (kc * 2 + ktp < 19) {
        short8 aF = *(const short8*)(A + r * 128 + ((ktp * 64 + (lq << 4)) ^ swA));
#pragma unroll
        for (int nt = 0; nt < 7; ++nt) {
          short8 bF = *(const short8*)(Bf + ((size_t)((nt * 2 + ktp) * 64 + l)) * 8);
          acc[nt] = MFMA16(aF, bF, acc[nt]);
        }
      }
    }
    __syncthreads();
  }
#pragma unroll
  for (int nt = 0; nt < 7; ++nt) {
    int col = nt * 16 + lc15;
    if (col < 100) {
      float bb = bdp[col];
#pragma unroll
      for (int e = 0; e < 4; ++e) {
        int row = w * 16 + lq * 4 + e;
        out[(size_t)(mblk * 64 + row) * 100 + col] = tanhx(acc[nt][e] + bb);
      }
    }
  }
}

// ---------------------------------------------------------------------------
extern "C" void kernel_launch(void* const* d_in, const int* in_sizes, int n_in,
                              void* d_out, int out_size, void* d_ws, size_t ws_size,
                              hipStream_t stream)
{
  (void)in_sizes; (void)n_in;
  const float* x  = (const float*)d_in[0];
  const float* Wf = (const float*)d_in[1];
  const float* Uf = (const float*)d_in[2];
  const float* bf = (const float*)d_in[3];
  const float* Wb = (const float*)d_in[4];
  const float* Ub = (const float*)d_in[5];
  const float* bb = (const float*)d_in[6];
  const float* Wd = (const float*)d_in[7];
  const float* bd = (const float*)d_in[8];
  float* out = (float*)d_out;
  char* ws = (char*)d_ws;

  hipError_t e1 = hipFuncSetAttribute((const void*)k_scan,
      hipFuncAttributeMaxDynamicSharedMemorySize, 143360);

  if (ws_size < WS_NEED || e1 != hipSuccess) {
    // Diagnostic: absmax will read ~ (ws_MB + 100000*attr_fail)
    float code = (float)(ws_size >> 20) + (e1 != hipSuccess ? 100000.f : 0.f);
    int n = out_size;
    hipLaunchKernelGGL(k_sentinel, dim3((n + 255) / 256), dim3(256), 0, stream,
                       out, code, n);
    return;
  }

  u16*   WT      = (u16*)(ws + OFF_WT);
  u16*   UT      = (u16*)(ws + OFF_UT);
  float* b0p     = (float*)(ws + OFF_B0P);
  float* b1p     = (float*)(ws + OFF_B1P);
  u16*   WdT     = (u16*)(ws + OFF_WDT);
  float* bdp     = (float*)(ws + OFF_BDP);
  float* mask    = (float*)(ws + OFF_MASK);
  u16*   h_state = (u16*)(ws + OFF_HSTATE);
  u32*   flags   = (u32*)(ws + OFF_FLAGS);
  u16*   xbf     = (u16*)(ws + OFF_XBF);
  u16*   h_all   = (u16*)(ws + OFF_HALL);

  // zero h_state + flags (contiguous region)
  hipMemsetAsync(ws + OFF_HSTATE, 0, 327680 + 16384, stream);

  hipLaunchKernelGGL(k_prep, dim3(2048), dim3(256), 0, stream,
                     Wf, Uf, bf, Wb, Ub, bb, Wd, bd, WT, UT, b0p, b1p, WdT, bdp);
  hipLaunchKernelGGL(k_xbf, dim3(16384), dim3(256), 0, stream, x, xbf, mask);
  hipLaunchKernelGGL(k_scan, dim3(96), dim3(256), 143360, stream,
                     UT, WT, b0p, b1p, xbf, mask, h_state, h_all, flags);
  hipLaunchKernelGGL(k_dense, dim3(1024), dim3(256), 0, stream,
                     h_all, WdT, bdp, out);
}